// Round 1
// baseline (43.212 us; speedup 1.0000x reference)
//
#include <hip/hip_runtime.h>
#include <hip/hip_bf16.h>

#define BATCH    512
#define IN_WIDTH 4096
#define OUT_F    4096
#define FAN_IN   128

// ---------------------------------------------------------------------------
// Kernel A: transpose input [BATCH][IN_WIDTH] f32 -> inT [IN_WIDTH][BATCH] bf16
// Standard 32x32 LDS-tiled transpose, +1 pad to kill bank conflicts.
// ---------------------------------------------------------------------------
__global__ __launch_bounds__(256) void k_transpose_in(const float* __restrict__ in,
                                                      __hip_bfloat16* __restrict__ inT) {
  __shared__ float tile[32][33];
  const int jt = blockIdx.x * 32;   // column (index-space) tile
  const int bt = blockIdx.y * 32;   // batch tile
  const int tx = threadIdx.x;       // 0..31
  const int ty = threadIdx.y;       // 0..7
#pragma unroll
  for (int r = 0; r < 32; r += 8) {
    // tile[b_local][j_local]
    tile[ty + r][tx] = in[(size_t)(bt + ty + r) * IN_WIDTH + (jt + tx)];
  }
  __syncthreads();
#pragma unroll
  for (int r = 0; r < 32; r += 8) {
    // inT[j][b] = input[b][j] ; value at (b = bt+tx, j = jt+ty+r) = tile[tx][ty+r]
    inT[(size_t)(jt + ty + r) * BATCH + (bt + tx)] = __float2bfloat16(tile[tx][ty + r]);
  }
}

// ---------------------------------------------------------------------------
// Kernel B: gather + FMA.  One block per output feature o.
//   outT[o][b] = bias[o] + sum_f inT[idx[o,f]][b] * weight[o,f]
// idx/weight loads are block-uniform -> scalar loads. Each thread owns
// batches {2t, 2t+1}, loaded as one uint32 (2 x bf16), coalesced per wave.
// ---------------------------------------------------------------------------
__global__ __launch_bounds__(256) void k_gather_fma(const __hip_bfloat16* __restrict__ inT,
                                                    const float* __restrict__ weight,
                                                    const float* __restrict__ bias,
                                                    const int* __restrict__ idx,
                                                    float* __restrict__ outT) {
  const int o = blockIdx.x;
  const int t = threadIdx.x;                 // 0..255 -> batches 2t, 2t+1
  const int* __restrict__ idxo = idx + (size_t)o * FAN_IN;
  const float* __restrict__ wo = weight + (size_t)o * FAN_IN;
  const uint16_t* __restrict__ inTu = reinterpret_cast<const uint16_t*>(inT);

  float acc0 = 0.f, acc1 = 0.f;
#pragma unroll 8
  for (int f = 0; f < FAN_IN; ++f) {
    const int   j = idxo[f];                 // uniform -> s_load
    const float w = wo[f];                   // uniform -> s_load
    const uint32_t v = *reinterpret_cast<const uint32_t*>(inTu + (size_t)j * BATCH + 2 * t);
    const float lo = __uint_as_float(v << 16);          // bf16 -> f32, element b=2t
    const float hi = __uint_as_float(v & 0xffff0000u);  // element b=2t+1
    acc0 = fmaf(lo, w, acc0);
    acc1 = fmaf(hi, w, acc1);
  }
  const float bz = bias[o];
  float2 r = make_float2(acc0 + bz, acc1 + bz);
  *reinterpret_cast<float2*>(outT + (size_t)o * BATCH + 2 * t) = r;
}

// ---------------------------------------------------------------------------
// Kernel C: transpose outT [OUT_F][BATCH] f32 -> out [BATCH][OUT_F] f32
// ---------------------------------------------------------------------------
__global__ __launch_bounds__(256) void k_transpose_out(const float* __restrict__ outT,
                                                       float* __restrict__ out) {
  __shared__ float tile[32][33];
  const int ot = blockIdx.x * 32;
  const int bt = blockIdx.y * 32;
  const int tx = threadIdx.x;
  const int ty = threadIdx.y;
#pragma unroll
  for (int r = 0; r < 32; r += 8) {
    // tile[o_local][b_local]
    tile[ty + r][tx] = outT[(size_t)(ot + ty + r) * BATCH + (bt + tx)];
  }
  __syncthreads();
#pragma unroll
  for (int r = 0; r < 32; r += 8) {
    // out[b][o], b = bt+ty+r, o = ot+tx  -> value = tile[tx][ty+r]
    out[(size_t)(bt + ty + r) * OUT_F + (ot + tx)] = tile[tx][ty + r];
  }
}

extern "C" void kernel_launch(void* const* d_in, const int* in_sizes, int n_in,
                              void* d_out, int out_size, void* d_ws, size_t ws_size,
                              hipStream_t stream) {
  const float* input  = (const float*)d_in[0];   // [512][4096] f32
  const float* weight = (const float*)d_in[1];   // [4096][128] f32
  const float* bias   = (const float*)d_in[2];   // [4096]      f32
  const int*   idx    = (const int*)d_in[3];     // [4096][128] int32 (harness narrows int64)
  float* out = (float*)d_out;                    // [512][4096] f32

  // Workspace layout: inT (bf16, 4 MB) | outT (f32, 8 MB)
  __hip_bfloat16* inT = (__hip_bfloat16*)d_ws;
  float* outT = (float*)((char*)d_ws + (size_t)IN_WIDTH * BATCH * sizeof(__hip_bfloat16));

  dim3 tblk(32, 8);
  k_transpose_in<<<dim3(IN_WIDTH / 32, BATCH / 32), tblk, 0, stream>>>(input, inT);
  k_gather_fma<<<dim3(OUT_F), dim3(256), 0, stream>>>(inT, weight, bias, idx, outT);
  k_transpose_out<<<dim3(OUT_F / 32, BATCH / 32), tblk, 0, stream>>>(outT, out);
}